// Round 1
// baseline (617.638 us; speedup 1.0000x reference)
//
#include <hip/hip_runtime.h>
#include <hip/hip_bf16.h>

#define Bc 8
#define Sc 2048
#define Hc 8
#define Dc 64
#define Ec 512
#define NTc 64
#define Tc (Bc*Sc)
#define N1c (4*Hc*Dc)

typedef float f32x4 __attribute__((ext_vector_type(4)));
typedef __bf16 bf16x8 __attribute__((ext_vector_type(8)));
typedef short short8 __attribute__((ext_vector_type(8)));

__device__ __forceinline__ unsigned short f2bf(float f){
  unsigned int u = __float_as_uint(f);
  u += 0x7fffu + ((u >> 16) & 1u);
  return (unsigned short)(u >> 16);
}
__device__ __forceinline__ float silu_f(float x){
  return x * __builtin_amdgcn_rcpf(1.f + __expf(-x));
}
__device__ __forceinline__ bf16x8 ldb8(const unsigned short* p){
  return __builtin_bit_cast(bf16x8, *(const short8*)p);
}
__device__ __forceinline__ f32x4 mfma16(bf16x8 a, bf16x8 b, f32x4 c){
  return __builtin_amdgcn_mfma_f32_16x16x32_bf16(a, b, c, 0, 0, 0);
}

// ---------------- transpose + cast fp32 -> bf16 : out[c][r] = in[r][c] ----------------
__global__ __launch_bounds__(1024) void k_transpose_cast(const float* __restrict__ in,
                                                         unsigned short* __restrict__ out,
                                                         int R, int C){
  __shared__ float tile[32][33];
  int tx = threadIdx.x, ty = threadIdx.y;
  int c0 = blockIdx.x * 32, r0 = blockIdx.y * 32;
  tile[ty][tx] = in[(size_t)(r0 + ty) * C + c0 + tx];
  __syncthreads();
  out[(size_t)(c0 + ty) * R + r0 + tx] = f2bf(tile[tx][ty]);
}

// ---------------- input layernorm -> bf16 (one wave per row of 512) ----------------
__global__ __launch_bounds__(256) void k_ln_in(const float* __restrict__ x, const float* __restrict__ g,
                                               const float* __restrict__ b, unsigned short* __restrict__ xn){
  int lane = threadIdx.x & 63;
  int row = blockIdx.x * 4 + (threadIdx.x >> 6);
  const float* xr = x + (size_t)row * Ec + lane * 8;
  float4 v0 = *(const float4*)xr;
  float4 v1 = *(const float4*)(xr + 4);
  float vv[8] = {v0.x, v0.y, v0.z, v0.w, v1.x, v1.y, v1.z, v1.w};
  float s = 0.f, ss = 0.f;
  #pragma unroll
  for (int j = 0; j < 8; ++j){ s += vv[j]; ss += vv[j] * vv[j]; }
  #pragma unroll
  for (int m = 1; m < 64; m <<= 1){ s += __shfl_xor(s, m); ss += __shfl_xor(ss, m); }
  float mu = s * (1.f / Ec);
  float rs = rsqrtf(ss * (1.f / Ec) - mu * mu + 1e-5f);
  int c = lane * 8;
  short8 o;
  #pragma unroll
  for (int j = 0; j < 8; ++j) o[j] = (short)f2bf((vv[j] - mu) * rs * g[c + j] + b[c + j]);
  *(short8*)(xn + (size_t)row * Ec + c) = o;
}

// ---------------- ln(attn_out) * u -> bf16 ----------------
__global__ __launch_bounds__(256) void k_ln_mul(const float* __restrict__ att, const float* __restrict__ g,
                                                const float* __restrict__ b, const float* __restrict__ u,
                                                unsigned short* __restrict__ par){
  int lane = threadIdx.x & 63;
  int row = blockIdx.x * 4 + (threadIdx.x >> 6);
  const float* xr = att + (size_t)row * Ec + lane * 8;
  float4 v0 = *(const float4*)xr;
  float4 v1 = *(const float4*)(xr + 4);
  const float* ur = u + (size_t)row * Ec + lane * 8;
  float4 u0 = *(const float4*)ur;
  float4 u1 = *(const float4*)(ur + 4);
  float vv[8] = {v0.x, v0.y, v0.z, v0.w, v1.x, v1.y, v1.z, v1.w};
  float uu[8] = {u0.x, u0.y, u0.z, u0.w, u1.x, u1.y, u1.z, u1.w};
  float s = 0.f, ss = 0.f;
  #pragma unroll
  for (int j = 0; j < 8; ++j){ s += vv[j]; ss += vv[j] * vv[j]; }
  #pragma unroll
  for (int m = 1; m < 64; m <<= 1){ s += __shfl_xor(s, m); ss += __shfl_xor(ss, m); }
  float mu = s * (1.f / Ec);
  float rs = rsqrtf(ss * (1.f / Ec) - mu * mu + 1e-5f);
  int c = lane * 8;
  short8 o;
  #pragma unroll
  for (int j = 0; j < 8; ++j) o[j] = (short)f2bf(uu[j] * ((vv[j] - mu) * rs * g[c + j] + b[c + j]));
  *(short8*)(par + (size_t)row * Ec + c) = o;
}

// ---------------- GEMM1: mixed = silu(xn @ w_uvqk + b); scatter u,v^T,q,k ----------------
// wave tile: 32(M) x 64(N), K=512. A:[T,512] bf16 row-major, BT:[2048,512] bf16.
__global__ __launch_bounds__(256) void k_gemm_uvqk(const unsigned short* __restrict__ A,
                                                   const unsigned short* __restrict__ BT,
                                                   const float* __restrict__ bias,
                                                   float* __restrict__ u_out,
                                                   unsigned short* __restrict__ vT,
                                                   unsigned short* __restrict__ qb,
                                                   unsigned short* __restrict__ kb){
  int lane = threadIdx.x & 63;
  int lm = lane & 15, quad = lane >> 4;
  int w = threadIdx.x >> 6;
  int n0 = blockIdx.x * 64;
  int m0 = blockIdx.y * 128 + w * 32;
  const unsigned short* a0p = A + (size_t)(m0 + lm) * Ec + quad * 8;
  const unsigned short* a1p = a0p + 16 * Ec;
  const unsigned short* bp0 = BT + (size_t)(n0 + lm) * Ec + quad * 8;
  f32x4 acc[2][4] = {};
  #pragma unroll 4
  for (int k0 = 0; k0 < Ec; k0 += 32){
    bf16x8 a0 = ldb8(a0p + k0);
    bf16x8 a1 = ldb8(a1p + k0);
    #pragma unroll
    for (int t = 0; t < 4; ++t){
      bf16x8 bb = ldb8(bp0 + (size_t)t * 16 * Ec + k0);
      acc[0][t] = mfma16(a0, bb, acc[0][t]);
      acc[1][t] = mfma16(a1, bb, acc[1][t]);
    }
  }
  #pragma unroll
  for (int t = 0; t < 4; ++t){
    int col = n0 + t * 16 + lm;
    float bv = bias[col];
    int cat = col >> 9;
    int c = col & 511, h = c >> 6, d = c & 63;
    #pragma unroll
    for (int i = 0; i < 2; ++i){
      #pragma unroll
      for (int r = 0; r < 4; ++r){
        int row = m0 + i * 16 + quad * 4 + r;
        float val = silu_f(acc[i][t][r] + bv);
        if (cat == 0){
          u_out[(size_t)row * Ec + col] = val;
        } else {
          int bb_ = row >> 11, s = row & (Sc - 1);
          unsigned short hv = f2bf(val);
          if (cat == 1)      vT[((size_t)(bb_ * Hc + h) * Dc + d) * Sc + s] = hv;
          else if (cat == 2) qb[((size_t)(bb_ * Hc + h) * Sc + s) * Dc + d] = hv;
          else               kb[((size_t)(bb_ * Hc + h) * Sc + s) * Dc + d] = hv;
        }
      }
    }
  }
}

// ---------------- HSTU silu attention ----------------
// grid (B*H, S/64); workgroup 4 waves, wave = 16 q rows, O = 16x64 per wave.
__global__ __launch_bounds__(256) void k_attn(const unsigned short* __restrict__ qb,
                                              const unsigned short* __restrict__ kb,
                                              const unsigned short* __restrict__ vT,
                                              float* __restrict__ att){
  __shared__ unsigned short P[4][16][32];
  int lane = threadIdx.x & 63, w = threadIdx.x >> 6;
  int lm = lane & 15, quad = lane >> 4;
  int bh = blockIdx.x;
  int qbase = blockIdx.y * 64;
  int qrow = qbase + w * 16;
  const unsigned short* qp = qb + ((size_t)bh * Sc + qrow + lm) * Dc + quad * 8;
  bf16x8 qa0 = ldb8(qp), qa1 = ldb8(qp + 32);
  const unsigned short* kbp = kb + (size_t)bh * Sc * Dc;
  const unsigned short* vbp = vT + (size_t)bh * Dc * Sc;
  f32x4 o[4] = {};
  int nkt = (qbase + 64) >> 5;   // key tiles of 32, cover keys [0, qbase+64)
  for (int kt = 0; kt < nkt; ++kt){
    int key0 = kt * 32;
    #pragma unroll
    for (int sub = 0; sub < 2; ++sub){
      int k16 = key0 + sub * 16;
      const unsigned short* kp = kbp + (size_t)(k16 + lm) * Dc + quad * 8;
      f32x4 sc = {0.f, 0.f, 0.f, 0.f};
      sc = mfma16(qa0, ldb8(kp), sc);
      sc = mfma16(qa1, ldb8(kp + 32), sc);
      int kg = k16 + lm;
      #pragma unroll
      for (int r = 0; r < 4; ++r){
        int qg = qrow + quad * 4 + r;
        bool ok = (kg <= qg) && ((kg < Sc - NTc) || (kg == qg));
        float p = ok ? silu_f(sc[r] * 0.125f) * (1.f / Sc) : 0.f;
        P[w][quad * 4 + r][sub * 16 + lm] = f2bf(p);
      }
    }
    // same-wave LDS round-trip: C-layout -> A-layout (DS ops in-order within a wave)
    bf16x8 pa = ldb8(&P[w][lm][quad * 8]);
    #pragma unroll
    for (int t = 0; t < 4; ++t){
      const unsigned short* vp = vbp + (size_t)(t * 16 + lm) * Sc + key0 + quad * 8;
      o[t] = mfma16(pa, ldb8(vp), o[t]);
    }
  }
  int bb_ = bh >> 3, hh = bh & 7;
  #pragma unroll
  for (int t = 0; t < 4; ++t){
    int d = t * 16 + lm;
    #pragma unroll
    for (int r = 0; r < 4; ++r){
      int s = qrow + quad * 4 + r;
      att[((size_t)(bb_ * Sc + s) * Hc + hh) * Dc + d] = o[t][r];
    }
  }
}

// ---------------- GEMM2: out = par @ w_proj + x ----------------
__global__ __launch_bounds__(256) void k_gemm_proj(const unsigned short* __restrict__ A,
                                                   const unsigned short* __restrict__ BT,
                                                   const float* __restrict__ x,
                                                   float* __restrict__ out){
  int lane = threadIdx.x & 63;
  int lm = lane & 15, quad = lane >> 4;
  int w = threadIdx.x >> 6;
  int n0 = blockIdx.x * 64;
  int m0 = blockIdx.y * 128 + w * 32;
  const unsigned short* a0p = A + (size_t)(m0 + lm) * Ec + quad * 8;
  const unsigned short* a1p = a0p + 16 * Ec;
  const unsigned short* bp0 = BT + (size_t)(n0 + lm) * Ec + quad * 8;
  f32x4 acc[2][4] = {};
  #pragma unroll 4
  for (int k0 = 0; k0 < Ec; k0 += 32){
    bf16x8 a0 = ldb8(a0p + k0);
    bf16x8 a1 = ldb8(a1p + k0);
    #pragma unroll
    for (int t = 0; t < 4; ++t){
      bf16x8 bb = ldb8(bp0 + (size_t)t * 16 * Ec + k0);
      acc[0][t] = mfma16(a0, bb, acc[0][t]);
      acc[1][t] = mfma16(a1, bb, acc[1][t]);
    }
  }
  #pragma unroll
  for (int t = 0; t < 4; ++t){
    int col = n0 + t * 16 + lm;
    #pragma unroll
    for (int i = 0; i < 2; ++i){
      #pragma unroll
      for (int r = 0; r < 4; ++r){
        int row = m0 + i * 16 + quad * 4 + r;
        out[(size_t)row * Ec + col] = acc[i][t][r] + x[(size_t)row * Ec + col];
      }
    }
  }
}

extern "C" void kernel_launch(void* const* d_in, const int* in_sizes, int n_in,
                              void* d_out, int out_size, void* d_ws, size_t ws_size,
                              hipStream_t stream){
  (void)in_sizes; (void)n_in; (void)out_size; (void)ws_size;
  const float* x        = (const float*)d_in[0];
  const float* w_uvqk   = (const float*)d_in[1];
  const float* b_uvqk   = (const float*)d_in[2];
  const float* ln_in_w  = (const float*)d_in[3];
  const float* ln_in_b  = (const float*)d_in[4];
  const float* ln_out_w = (const float*)d_in[5];
  const float* ln_out_b = (const float*)d_in[6];
  const float* w_proj   = (const float*)d_in[7];
  float* out = (float*)d_out;

  char* ws = (char*)d_ws;
  unsigned short* xn  = (unsigned short*)(ws + 0);          // 16 MB, reused as `par` later
  unsigned short* wuT = (unsigned short*)(ws + 16777216);   // 2 MB
  unsigned short* wpT = (unsigned short*)(ws + 18874368);   // 0.5 MB
  float*          ub  = (float*)(ws + 19398656);            // 32 MB
  unsigned short* qbf = (unsigned short*)(ws + 52953088);   // 16 MB
  unsigned short* kbf = (unsigned short*)(ws + 69730304);   // 16 MB
  unsigned short* vTt = (unsigned short*)(ws + 86507520);   // 16 MB
  float*          att = (float*)(ws + 103284736);           // 32 MB (ends 136,839,168)

  dim3 tb(32, 32);
  k_transpose_cast<<<dim3(N1c / 32, Ec / 32), tb, 0, stream>>>(w_uvqk, wuT, Ec, N1c);
  k_transpose_cast<<<dim3(Ec / 32, Ec / 32), tb, 0, stream>>>(w_proj, wpT, Ec, Ec);
  k_ln_in<<<Tc / 4, 256, 0, stream>>>(x, ln_in_w, ln_in_b, xn);
  k_gemm_uvqk<<<dim3(N1c / 64, Tc / 128), 256, 0, stream>>>(xn, wuT, b_uvqk, ub, vTt, qbf, kbf);
  k_attn<<<dim3(Bc * Hc, Sc / 64), 256, 0, stream>>>(qbf, kbf, vTt, att);
  k_ln_mul<<<Tc / 4, 256, 0, stream>>>(att, ln_out_w, ln_out_b, ub, xn);
  k_gemm_proj<<<dim3(Ec / 64, Tc / 128), 256, 0, stream>>>(xn, wpT, x, out);
}

// Round 2
// 613.888 us; speedup vs baseline: 1.0061x; 1.0061x over previous
//
#include <hip/hip_runtime.h>
#include <hip/hip_bf16.h>

#define Bc 8
#define Sc 2048
#define Hc 8
#define Dc 64
#define Ec 512
#define NTc 64
#define Tc (Bc*Sc)
#define N1c (4*Hc*Dc)
#define HISTc (Sc - NTc)

typedef float f32x4 __attribute__((ext_vector_type(4)));
typedef __bf16 bf16x8 __attribute__((ext_vector_type(8)));
typedef short short8 __attribute__((ext_vector_type(8)));
typedef short s4v __attribute__((ext_vector_type(4)));

__device__ __forceinline__ unsigned short f2bf(float f){
  unsigned int u = __float_as_uint(f);
  u += 0x7fffu + ((u >> 16) & 1u);
  return (unsigned short)(u >> 16);
}
__device__ __forceinline__ float silu_f(float x){
  return x * __builtin_amdgcn_rcpf(1.f + __expf(-x));
}
__device__ __forceinline__ bf16x8 ldb8(const unsigned short* p){
  return __builtin_bit_cast(bf16x8, *(const short8*)p);
}
__device__ __forceinline__ f32x4 mfma16(bf16x8 a, bf16x8 b, f32x4 c){
  return __builtin_amdgcn_mfma_f32_16x16x32_bf16(a, b, c, 0, 0, 0);
}

// ---------------- transpose + cast fp32 -> bf16 : out[c][r] = in[r][c] ----------------
__global__ __launch_bounds__(1024) void k_transpose_cast(const float* __restrict__ in,
                                                         unsigned short* __restrict__ out,
                                                         int R, int C){
  __shared__ float tile[32][33];
  int tx = threadIdx.x, ty = threadIdx.y;
  int c0 = blockIdx.x * 32, r0 = blockIdx.y * 32;
  tile[ty][tx] = in[(size_t)(r0 + ty) * C + c0 + tx];
  __syncthreads();
  out[(size_t)(c0 + ty) * R + r0 + tx] = f2bf(tile[tx][ty]);
}

// ---------------- input layernorm -> bf16 (one wave per row of 512) ----------------
__global__ __launch_bounds__(256) void k_ln_in(const float* __restrict__ x, const float* __restrict__ g,
                                               const float* __restrict__ b, unsigned short* __restrict__ xn){
  int lane = threadIdx.x & 63;
  int row = blockIdx.x * 4 + (threadIdx.x >> 6);
  const float* xr = x + (size_t)row * Ec + lane * 8;
  float4 v0 = *(const float4*)xr;
  float4 v1 = *(const float4*)(xr + 4);
  float vv[8] = {v0.x, v0.y, v0.z, v0.w, v1.x, v1.y, v1.z, v1.w};
  float s = 0.f, ss = 0.f;
  #pragma unroll
  for (int j = 0; j < 8; ++j){ s += vv[j]; ss += vv[j] * vv[j]; }
  #pragma unroll
  for (int m = 1; m < 64; m <<= 1){ s += __shfl_xor(s, m); ss += __shfl_xor(ss, m); }
  float mu = s * (1.f / Ec);
  float rs = rsqrtf(ss * (1.f / Ec) - mu * mu + 1e-5f);
  int c = lane * 8;
  short8 o;
  #pragma unroll
  for (int j = 0; j < 8; ++j) o[j] = (short)f2bf((vv[j] - mu) * rs * g[c + j] + b[c + j]);
  *(short8*)(xn + (size_t)row * Ec + c) = o;
}

// ---------------- ln(attn_out) * u -> bf16 ----------------
__global__ __launch_bounds__(256) void k_ln_mul(const float* __restrict__ att, const float* __restrict__ g,
                                                const float* __restrict__ b, const float* __restrict__ u,
                                                unsigned short* __restrict__ par){
  int lane = threadIdx.x & 63;
  int row = blockIdx.x * 4 + (threadIdx.x >> 6);
  const float* xr = att + (size_t)row * Ec + lane * 8;
  float4 v0 = *(const float4*)xr;
  float4 v1 = *(const float4*)(xr + 4);
  const float* ur = u + (size_t)row * Ec + lane * 8;
  float4 u0 = *(const float4*)ur;
  float4 u1 = *(const float4*)(ur + 4);
  float vv[8] = {v0.x, v0.y, v0.z, v0.w, v1.x, v1.y, v1.z, v1.w};
  float uu[8] = {u0.x, u0.y, u0.z, u0.w, u1.x, u1.y, u1.z, u1.w};
  float s = 0.f, ss = 0.f;
  #pragma unroll
  for (int j = 0; j < 8; ++j){ s += vv[j]; ss += vv[j] * vv[j]; }
  #pragma unroll
  for (int m = 1; m < 64; m <<= 1){ s += __shfl_xor(s, m); ss += __shfl_xor(ss, m); }
  float mu = s * (1.f / Ec);
  float rs = rsqrtf(ss * (1.f / Ec) - mu * mu + 1e-5f);
  int c = lane * 8;
  short8 o;
  #pragma unroll
  for (int j = 0; j < 8; ++j) o[j] = (short)f2bf(uu[j] * ((vv[j] - mu) * rs * g[c + j] + b[c + j]));
  *(short8*)(par + (size_t)row * Ec + c) = o;
}

// ---------------- GEMM1: mixed = silu(xn @ w_uvqk + b); scatter u,v^T,q,k ----------------
// q is pre-scaled by alpha=0.125 (exact pow2, folded out of attention inner loop).
__global__ __launch_bounds__(256) void k_gemm_uvqk(const unsigned short* __restrict__ A,
                                                   const unsigned short* __restrict__ BT,
                                                   const float* __restrict__ bias,
                                                   float* __restrict__ u_out,
                                                   unsigned short* __restrict__ vT,
                                                   unsigned short* __restrict__ qb,
                                                   unsigned short* __restrict__ kb){
  int lane = threadIdx.x & 63;
  int lm = lane & 15, quad = lane >> 4;
  int w = threadIdx.x >> 6;
  int n0 = blockIdx.x * 64;
  int m0 = blockIdx.y * 128 + w * 32;
  const unsigned short* a0p = A + (size_t)(m0 + lm) * Ec + quad * 8;
  const unsigned short* a1p = a0p + 16 * Ec;
  const unsigned short* bp0 = BT + (size_t)(n0 + lm) * Ec + quad * 8;
  f32x4 acc[2][4] = {};
  #pragma unroll 4
  for (int k0 = 0; k0 < Ec; k0 += 32){
    bf16x8 a0 = ldb8(a0p + k0);
    bf16x8 a1 = ldb8(a1p + k0);
    #pragma unroll
    for (int t = 0; t < 4; ++t){
      bf16x8 bb = ldb8(bp0 + (size_t)t * 16 * Ec + k0);
      acc[0][t] = mfma16(a0, bb, acc[0][t]);
      acc[1][t] = mfma16(a1, bb, acc[1][t]);
    }
  }
  #pragma unroll
  for (int t = 0; t < 4; ++t){
    int col = n0 + t * 16 + lm;
    float bv = bias[col];
    int cat = col >> 9;
    int c = col & 511, h = c >> 6, d = c & 63;
    #pragma unroll
    for (int i = 0; i < 2; ++i){
      #pragma unroll
      for (int r = 0; r < 4; ++r){
        int row = m0 + i * 16 + quad * 4 + r;
        float val = silu_f(acc[i][t][r] + bv);
        if (cat == 0){
          u_out[(size_t)row * Ec + col] = val;
        } else {
          int bb_ = row >> 11, s = row & (Sc - 1);
          unsigned short hv = f2bf(cat == 2 ? val * 0.125f : val);
          if (cat == 1)      vT[((size_t)(bb_ * Hc + h) * Dc + d) * Sc + s] = hv;
          else if (cat == 2) qb[((size_t)(bb_ * Hc + h) * Sc + s) * Dc + d] = hv;
          else               kb[((size_t)(bb_ * Hc + h) * Sc + s) * Dc + d] = hv;
        }
      }
    }
  }
}

// ---------------- HSTU silu attention (S^T trick: vector P store/load) ----------------
// grid (B*H, S/64); 4 waves, wave = 16 q rows, O = 16x64 per wave.
// QK computed transposed: mfma(A=K, B=Q) -> lane holds S^T[key=quad*4+r][q=lm],
// i.e. 4 consecutive t per lane -> ds_write_b64 into P[q][t], read back ds_read_b128
// as the PV A-fragment. 1/S applied at O-write (linear); alpha pre-folded into q.
#define PSTR 40   // 32 + 8 pad (u16): write base banks 2-way only (free)
__global__ __launch_bounds__(256) void k_attn(const unsigned short* __restrict__ qb,
                                              const unsigned short* __restrict__ kb,
                                              const unsigned short* __restrict__ vT,
                                              float* __restrict__ att){
  __shared__ unsigned short P[4][16 * PSTR];
  int lane = threadIdx.x & 63, w = threadIdx.x >> 6;
  int lm = lane & 15, quad = lane >> 4;
  int bh = blockIdx.x;
  int qbase = blockIdx.y * 64;
  int qrow = qbase + w * 16;
  const unsigned short* qp = qb + ((size_t)bh * Sc + qrow + lm) * Dc + quad * 8;
  bf16x8 qa0 = ldb8(qp), qa1 = ldb8(qp + 32);
  const unsigned short* kbp = kb + (size_t)bh * Sc * Dc;
  const unsigned short* vbp = vT + (size_t)bh * Dc * Sc;
  unsigned short* Pm = P[w];
  f32x4 o[4] = {};
  int qg = qrow + lm;
  int nkt = (qrow + 16 + 31) >> 5;          // per-wave: keys in [0, qrow+16)
  for (int kt = 0; kt < nkt; ++kt){
    int key0 = kt * 32;
    // QK^T (transposed): two 16-key subtiles
    const unsigned short* kp0 = kbp + (size_t)(key0 + lm) * Dc + quad * 8;
    const unsigned short* kp1 = kp0 + 16 * Dc;
    f32x4 s0 = {0.f,0.f,0.f,0.f}, s1 = {0.f,0.f,0.f,0.f};
    s0 = mfma16(ldb8(kp0), qa0, s0);
    s0 = mfma16(ldb8(kp0 + 32), qa1, s0);
    s1 = mfma16(ldb8(kp1), qa0, s1);
    s1 = mfma16(ldb8(kp1 + 32), qa1, s1);
    bool full = (key0 + 31 <= qrow) && (key0 + 31 < HISTc);  // wave-uniform
    s4v p0, p1;
    if (full){
      #pragma unroll
      for (int r = 0; r < 4; ++r){
        p0[r] = (short)f2bf(silu_f(s0[r]));
        p1[r] = (short)f2bf(silu_f(s1[r]));
      }
    } else {
      #pragma unroll
      for (int r = 0; r < 4; ++r){
        int kg0 = key0 + quad * 4 + r, kg1 = kg0 + 16;
        bool ok0 = (kg0 <= qg) && ((kg0 < HISTc) || (kg0 == qg));
        bool ok1 = (kg1 <= qg) && ((kg1 < HISTc) || (kg1 == qg));
        p0[r] = ok0 ? (short)f2bf(silu_f(s0[r])) : (short)0;
        p1[r] = ok1 ? (short)f2bf(silu_f(s1[r])) : (short)0;
      }
    }
    *(s4v*)&Pm[lm * PSTR + quad * 4]      = p0;   // ds_write_b64
    *(s4v*)&Pm[lm * PSTR + 16 + quad * 4] = p1;   // ds_write_b64
    // same-wave LDS round-trip (DS ops in-order within a wave)
    bf16x8 pa = ldb8(&Pm[lm * PSTR + quad * 8]);  // ds_read_b128, A-frag P[q][t]
    #pragma unroll
    for (int t = 0; t < 4; ++t){
      const unsigned short* vp = vbp + (size_t)(t * 16 + lm) * Sc + key0 + quad * 8;
      o[t] = mfma16(pa, ldb8(vp), o[t]);
    }
  }
  int bb_ = bh >> 3, hh = bh & 7;
  #pragma unroll
  for (int t = 0; t < 4; ++t){
    int d = t * 16 + lm;
    #pragma unroll
    for (int r = 0; r < 4; ++r){
      int s = qrow + quad * 4 + r;
      att[((size_t)(bb_ * Sc + s) * Hc + hh) * Dc + d] = o[t][r] * (1.f / Sc);
    }
  }
}

// ---------------- GEMM2: out = par @ w_proj + x ----------------
__global__ __launch_bounds__(256) void k_gemm_proj(const unsigned short* __restrict__ A,
                                                   const unsigned short* __restrict__ BT,
                                                   const float* __restrict__ x,
                                                   float* __restrict__ out){
  int lane = threadIdx.x & 63;
  int lm = lane & 15, quad = lane >> 4;
  int w = threadIdx.x >> 6;
  int n0 = blockIdx.x * 64;
  int m0 = blockIdx.y * 128 + w * 32;
  const unsigned short* a0p = A + (size_t)(m0 + lm) * Ec + quad * 8;
  const unsigned short* a1p = a0p + 16 * Ec;
  const unsigned short* bp0 = BT + (size_t)(n0 + lm) * Ec + quad * 8;
  f32x4 acc[2][4] = {};
  #pragma unroll 4
  for (int k0 = 0; k0 < Ec; k0 += 32){
    bf16x8 a0 = ldb8(a0p + k0);
    bf16x8 a1 = ldb8(a1p + k0);
    #pragma unroll
    for (int t = 0; t < 4; ++t){
      bf16x8 bb = ldb8(bp0 + (size_t)t * 16 * Ec + k0);
      acc[0][t] = mfma16(a0, bb, acc[0][t]);
      acc[1][t] = mfma16(a1, bb, acc[1][t]);
    }
  }
  #pragma unroll
  for (int t = 0; t < 4; ++t){
    int col = n0 + t * 16 + lm;
    #pragma unroll
    for (int i = 0; i < 2; ++i){
      #pragma unroll
      for (int r = 0; r < 4; ++r){
        int row = m0 + i * 16 + quad * 4 + r;
        out[(size_t)row * Ec + col] = acc[i][t][r] + x[(size_t)row * Ec + col];
      }
    }
  }
}

extern "C" void kernel_launch(void* const* d_in, const int* in_sizes, int n_in,
                              void* d_out, int out_size, void* d_ws, size_t ws_size,
                              hipStream_t stream){
  (void)in_sizes; (void)n_in; (void)out_size; (void)ws_size;
  const float* x        = (const float*)d_in[0];
  const float* w_uvqk   = (const float*)d_in[1];
  const float* b_uvqk   = (const float*)d_in[2];
  const float* ln_in_w  = (const float*)d_in[3];
  const float* ln_in_b  = (const float*)d_in[4];
  const float* ln_out_w = (const float*)d_in[5];
  const float* ln_out_b = (const float*)d_in[6];
  const float* w_proj   = (const float*)d_in[7];
  float* out = (float*)d_out;

  char* ws = (char*)d_ws;
  unsigned short* xn  = (unsigned short*)(ws + 0);          // 16 MB, reused as `par` later
  unsigned short* wuT = (unsigned short*)(ws + 16777216);   // 2 MB
  unsigned short* wpT = (unsigned short*)(ws + 18874368);   // 0.5 MB
  float*          ub  = (float*)(ws + 19398656);            // 32 MB
  unsigned short* qbf = (unsigned short*)(ws + 52953088);   // 16 MB
  unsigned short* kbf = (unsigned short*)(ws + 69730304);   // 16 MB
  unsigned short* vTt = (unsigned short*)(ws + 86507520);   // 16 MB
  float*          att = (float*)(ws + 103284736);           // 32 MB (ends 136,839,168)

  dim3 tb(32, 32);
  k_transpose_cast<<<dim3(N1c / 32, Ec / 32), tb, 0, stream>>>(w_uvqk, wuT, Ec, N1c);
  k_transpose_cast<<<dim3(Ec / 32, Ec / 32), tb, 0, stream>>>(w_proj, wpT, Ec, Ec);
  k_ln_in<<<Tc / 4, 256, 0, stream>>>(x, ln_in_w, ln_in_b, xn);
  k_gemm_uvqk<<<dim3(N1c / 64, Tc / 128), 256, 0, stream>>>(xn, wuT, b_uvqk, ub, vTt, qbf, kbf);
  k_attn<<<dim3(Bc * Hc, Sc / 64), 256, 0, stream>>>(qbf, kbf, vTt, att);
  k_ln_mul<<<Tc / 4, 256, 0, stream>>>(att, ln_out_w, ln_out_b, ub, xn);
  k_gemm_proj<<<dim3(Ec / 64, Tc / 128), 256, 0, stream>>>(xn, wpT, x, out);
}